// Round 10
// baseline (579.989 us; speedup 1.0000x reference)
//
#include <hip/hip_runtime.h>

// Problem constants
#define V_  32000
#define E_  256
#define H_  256
#define S_  128
#define B_  64
#define HID_ 30

typedef float f32x2 __attribute__((ext_vector_type(2)));

// Fast activations (v_exp_f32 + v_rcp_f32; ~3e-7 abs err). Round-1/7 evidence:
// LSTM-path precision changes do not move absmax (identical 0.0004882812).
__device__ __forceinline__ float sigmoid_fast(float x) {
    return __builtin_amdgcn_rcpf(1.f + __expf(-x));
}
__device__ __forceinline__ float fast_tanh(float x) {
    return 1.f - 2.f * __builtin_amdgcn_rcpf(1.f + __expf(2.f * x));
}
__device__ __forceinline__ float sigmoid_acc(float x) {
    return 1.0f / (1.0f + expf(-x));
}

// Fast-path exchange ops (64-bit scalar operands -> VGPR pairs).
// NOTE gfx950 assembler syntax: offset: immediate must precede cache flags.
// Producer: two plain dwordx2 stores (write-through L1 -> home XCD L2).
// Consumer: two sc0 loads (L1 bypass, reads shared XCD L2), one waitcnt.
//
// POLL STRUCTURE IS LOAD-BEARING (r1, r7 post-mortems): the serial
// fast-pair-then-slow-pair loop, both checked EVERY iteration, is the only
// cadence that has not regressed. r7's higher fast-load density + early
// issue caused L2 store-starvation on the polled line (detection ~36
// iters/step, FETCH 45MB->4.9GB). Do not restructure without a
// single-variable experiment.
__device__ __forceinline__ void store_l2x2(unsigned long long* p,
                                           unsigned long long a,
                                           unsigned long long b) {
    asm volatile("global_store_dwordx2 %2, %0, off\n\t"
                 "global_store_dwordx2 %2, %1, off offset:8"
                 :: "v"(a), "v"(b), "v"(p) : "memory");
}
__device__ __forceinline__ void load_l2x2(const unsigned long long* p,
                                          unsigned long long& a,
                                          unsigned long long& b) {
    asm volatile("global_load_dwordx2 %0, %2, off sc0\n\t"
                 "global_load_dwordx2 %1, %2, off offset:8 sc0\n\t"
                 "s_waitcnt vmcnt(0)"
                 : "=&v"(a), "=&v"(b) : "v"(p) : "memory");
}

// LDS-only barrier: orders LDS (h buffer) across the WG WITHOUT the vmcnt(0)
// drain __syncthreads() emits. Producers' LLC publishes / enc stores / x
// prefetches stay in flight across step boundaries.
__device__ __forceinline__ void barrier_lds() {
    asm volatile("s_waitcnt lgkmcnt(0)" ::: "memory");
    __builtin_amdgcn_s_barrier();
    __builtin_amdgcn_sched_barrier(0);
}

// Broadcast h-pair j (held by lane j) to all lanes via v_readlane (VALU),
// keeping the broadcast OFF the LDS pipe. j must be compile-time.
__device__ __forceinline__ f32x2 bcast_pair(int hxb, int hyb, int j) {
    return (f32x2){
        __int_as_float(__builtin_amdgcn_readlane(hxb, j)),
        __int_as_float(__builtin_amdgcn_readlane(hyb, j))};
}

// ---------------------------------------------------------------------------
// K0: build sT (per (dir, side) the last 16 cols 112..127 of each Whh row,
// transposed for coalesced streaming; plane q = dir*8+side*4+j) AND zero the
// exchange channels (Fch+Sch contiguous, 4MB) -- replaces the separate
// hipMemsetAsync dispatch (tag 0 != any expected tag >= 1).
// ---------------------------------------------------------------------------
__global__ __launch_bounds__(256) void prep_stream_kernel(
    const float* __restrict__ Whh_f, const float* __restrict__ Whh_b,
    float4* __restrict__ sT, unsigned long long* __restrict__ Fch) {
    int i = blockIdx.x * 256 + threadIdx.x;      // < 16*1024
    if (i < 16 * 1024) {
        int r = i & 1023;
        int q = i >> 10;                         // 0..15
        int j = q & 3;
        int side = (q >> 2) & 1;
        int dir = q >> 3;
        const float* Whh = dir ? Whh_b : Whh_f;
        const float* src = Whh + (size_t)r * H_ + side * 128 + 112 + 4 * j;
        sT[(size_t)q * 1024 + r] = make_float4(src[0], src[1], src[2], src[3]);
    }
    // zero Fch+Sch: 2*2097152 bytes = 524288 ullongs, 16384 threads
    for (size_t k = i; k < 524288; k += 16384) Fch[k] = 0ull;
}

// ---------------------------------------------------------------------------
// K1: f32 input-projection GEMM with fused embedding gather.
// 128x128 tile, 8x8 per thread, KC=32 via LDS. grid (512, 2), block 256.
// r9-verbatim (r7/r8 "prefetch" regressed: barrier vmcnt drain voids the
// overlap and +16 VGPRs under the (256,4) budget spills).
// ---------------------------------------------------------------------------
#define GKC 32
#define GLD 132

__global__ __launch_bounds__(256, 4) void gemm2_kernel(
    const int* __restrict__ concepts, const float* __restrict__ embedding,
    const float* __restrict__ Wih_f, const float* __restrict__ Wih_b,
    float* __restrict__ Xg) {
    __shared__ float As[GKC][GLD];
    __shared__ float Bs[GKC][GLD];
    const int dir = blockIdx.y;
    const float* Wih = dir ? Wih_b : Wih_f;
    const int mt = blockIdx.x >> 3;
    const int nt = blockIdx.x & 7;
    const int m0 = mt * 128, n0 = nt * 128;
    const int t = threadIdx.x;
    const int tm = (t & 15) * 4;
    const int tn = (t >> 4) * 4;

    int cid[4], rr[4];
#pragma unroll
    for (int i = 0; i < 4; ++i) {
        int flat = t + 256 * i;
        rr[i] = flat >> 3;
        cid[i] = concepts[m0 + rr[i]];
    }

    float acc[8][8];
#pragma unroll
    for (int i = 0; i < 8; ++i)
#pragma unroll
        for (int j = 0; j < 8; ++j) acc[i][j] = 0.f;

    for (int kk = 0; kk < E_; kk += GKC) {
        __syncthreads();
#pragma unroll
        for (int i = 0; i < 4; ++i) {
            int flat = t + 256 * i;
            int r = rr[i];
            int kq = (flat & 7) * 4;
            float4 av = *(const float4*)&embedding[(size_t)cid[i] * E_ + kk + kq];
            float4 bv = *(const float4*)&Wih[(size_t)(n0 + r) * E_ + kk + kq];
            As[kq + 0][r] = av.x; As[kq + 1][r] = av.y;
            As[kq + 2][r] = av.z; As[kq + 3][r] = av.w;
            Bs[kq + 0][r] = bv.x; Bs[kq + 1][r] = bv.y;
            Bs[kq + 2][r] = bv.z; Bs[kq + 3][r] = bv.w;
        }
        __syncthreads();
#pragma unroll
        for (int k = 0; k < GKC; ++k) {
            float4 a0 = *(const float4*)&As[k][tm];
            float4 a1 = *(const float4*)&As[k][tm + 64];
            float4 b0 = *(const float4*)&Bs[k][tn];
            float4 b1 = *(const float4*)&Bs[k][tn + 64];
            float am[8] = {a0.x, a0.y, a0.z, a0.w, a1.x, a1.y, a1.z, a1.w};
            float bn[8] = {b0.x, b0.y, b0.z, b0.w, b1.x, b1.y, b1.z, b1.w};
#pragma unroll
            for (int i = 0; i < 8; ++i)
#pragma unroll
                for (int j = 0; j < 8; ++j)
                    acc[i][j] = fmaf(am[i], bn[j], acc[i][j]);
        }
    }
    float* out = Xg + ((size_t)dir * 8192 + m0) * 1024 + n0;
#pragma unroll
    for (int i = 0; i < 8; ++i) {
        int mr = (i < 4) ? (tm + i) : (tm + 60 + i);
        *(float4*)&out[(size_t)mr * 1024 + tn] =
            make_float4(acc[i][0], acc[i][1], acc[i][2], acc[i][3]);
        *(float4*)&out[(size_t)mr * 1024 + tn + 64] =
            make_float4(acc[i][4], acc[i][5], acc[i][6], acc[i][7]);
    }
}

// ---------------------------------------------------------------------------
// K2: LSTM, K-split pair with dual-path (L2-fast + LLC-safe) exchange.
// 256 WGs x 512 thr (1 WG/CU), both dirs concurrent, cooperative launch.
// w: side = w>>7 (partner = w^128), P = w&127, dir = P&1, b = P>>1.
//
// r10: h broadcast moved OFF the LDS pipe. r9 counters showed the step time
// equals the LDS return-bandwidth (400KB/step/CU, 64% of it redundant
// broadcast quad reads). Now: each lane reads its OWN h-pair once
// (1 ds_read_b64; lane j holds pair j) and pairs are broadcast to all lanes
// via v_readlane (VALU->SGPR). LDS per thread/step: 50 b128 -> 18 b128 + 1
// b64. Everything else (poll, barrier, pins) is r9-byte-identical.
//
// Weight split per thread (2 rows rA,rB over the side's 128 cols = 64 pairs):
//   pairs  0..37 : registers (asm-pinned), pairs 38..55 : LDS float4-interleaved,
//   pairs 56..63 : registers (loop-invariant, hoisted). Producers have no
//   per-step VMEM loads.
// Row mapping (intra-wave gate pairing): wave=t>>6, lane=t&63, li=lane&31,
// half=lane>>5, qw=(wave&1)|((wave>>2)<<1), consumer iff ((wave>>1)&1)==side.
// hcol=128*hs+32*qw+li; rA=hcol+half*256; rB=rA+512. f,o handoff =
// __shfl_xor(.,32). ONE LDS-only barrier/step, h double-buffered.
// Poll: r6-verbatim serial dual-path (see note at store_l2x2).
// ---------------------------------------------------------------------------
#define RP_  38
#define LPD_ 18

__global__ __launch_bounds__(512)
__attribute__((amdgpu_waves_per_eu(2, 2)))
void lstm_ks3_kernel(
    const float* __restrict__ Xg,     // [2][8192][1024]
    const float* __restrict__ Whh_f, const float* __restrict__ Whh_b,
    const float* __restrict__ b_f, const float* __restrict__ b_b,
    const int* __restrict__ lens,
    float* __restrict__ enc,          // [B][S][512]
    unsigned long long* __restrict__ Fch,  // [P=128][2 par][2 prodside][512]
    unsigned long long* __restrict__ Sch,  // [P=128][2 par][2 prodside][512]
    const float4* __restrict__ sT) {  // [16][1024]
    extern __shared__ float4 Wl4[];   // [LPD_][512]
    __shared__ float h_sh[2][128];    // double-buffered own-side h (read s&1)
    const int w = blockIdx.x;
    const int side = w >> 7;
    const int P = w & 127;
    const int dir = P & 1, b = P >> 1;
    const int t = threadIdx.x;
    const int wav = t >> 6;
    const int lane = t & 63;
    const int li = lane & 31;
    const int half = lane >> 5;                    // 0:(i,g)  1:(f,o)
    const int qw = (wav & 1) | ((wav >> 2) << 1);  // 0..3 within cons/prod set
    const bool mine = (((wav >> 1) & 1) == side);  // consumer wave (uniform)
    const int hs = mine ? side : (side ^ 1);       // side of h-cols served
    const int hcol = (hs << 7) + (qw << 5) + li;   // h column 0..255
    const int rA = hcol + half * 256;              // i- or f-gate row
    const int rB = hcol + 512 + half * 256;        // g- or o-gate row
    const int base = side << 7;
    const int idx = (qw << 6) + lane;              // exchange slot 0..255
    const float* Whh = dir ? Whh_b : Whh_f;
    const int len = lens[b];

    // pin weights: rows rA, rB, own-side pair-cols [0,38) in regs
    f32x2 w0[RP_], w1[RP_];
    {
        const f32x2* p0 = (const f32x2*)(Whh + (size_t)rA * H_ + base);
        const f32x2* p1 = (const f32x2*)(Whh + (size_t)rB * H_ + base);
#pragma unroll
        for (int j = 0; j < RP_; ++j) { w0[j] = p0[j]; w1[j] = p1[j]; }
        // pairs [38,56) in LDS, rA/rB interleaved -> one b128 per pair
#pragma unroll
        for (int j = 0; j < LPD_; ++j) {
            f32x2 a = p0[RP_ + j], c2 = p1[RP_ + j];
            Wl4[j * 512 + t] = make_float4(a.x, a.y, c2.x, c2.y);
        }
    }
    // pairs 56..63: loop-invariant, pinned in regs as f32x2 (8 per row)
    const f32x2* sT2 = (const f32x2*)(sT + (size_t)(dir * 8 + side * 4) * 1024);
    f32x2 s0[8], s1[8];
#pragma unroll
    for (int k = 0; k < 4; ++k) {
        s0[2 * k]     = sT2[2 * (k * 1024 + rA)];
        s0[2 * k + 1] = sT2[2 * (k * 1024 + rA) + 1];
        s1[2 * k]     = sT2[2 * (k * 1024 + rB)];
        s1[2 * k + 1] = sT2[2 * (k * 1024 + rB) + 1];
    }
    // Keep pinned values live in the register file across the whole loop.
    // NOTE: 64-bit f32x2 ties compile; 128-bit float4 ties do not (r5).
#pragma unroll
    for (int j = 0; j < RP_; ++j) {
        asm volatile("" : "+v"(w0[j]), "+v"(w1[j]));
    }
#pragma unroll
    for (int k = 0; k < 8; ++k) {
        asm volatile("" : "+v"(s0[k]), "+v"(s1[k]));
    }
    const float* bias = dir ? b_b : b_f;
    const float bias0 = bias[rA], bias1 = bias[rB];

    // exchange base pointers (parity applied per step via +1024 elements)
    unsigned long long* fwb = Fch + (((size_t)P * 2 + 0) * 2 + side) * 512 + 2 * idx;
    const unsigned long long* frb =
        Fch + (((size_t)P * 2 + 0) * 2 + (side ^ 1)) * 512 + 2 * idx;
    unsigned long long* swb = Sch + (((size_t)P * 2 + 0) * 2 + side) * 512 + 2 * idx;
    const unsigned long long* srb =
        Sch + (((size_t)P * 2 + 0) * 2 + (side ^ 1)) * 512 + 2 * idx;

    if (t < 128) h_sh[0][t] = 0.f;
    float c = 0.f;                    // cell state (consumer lanes 0..31)
    __syncthreads();                  // full sync once (Wl4 + h init)

    // x prefetch (consumers only)
    int srow = dir ? (len - 1) : 0;   // len >= 1 guaranteed
    float x0 = 0.f, x1 = 0.f;
    if (mine) {
        const float* xp = Xg + ((size_t)dir * 8192 + (size_t)srow * B_ + b) * 1024;
        x0 = xp[rA]; x1 = xp[rB];
    }

    for (int s = 0; s < S_; ++s) {
        // next-step x prefetch
        int srow_n = 0;
        float x0n = 0.f, x1n = 0.f;
        if (s + 1 < S_) {
            int ns = s + 1;
            srow_n = dir ? ((ns < len) ? (len - 1 - ns) : ns) : ns;
            if (mine) {
                const float* xp =
                    Xg + ((size_t)dir * 8192 + (size_t)srow_n * B_ + b) * 1024;
                x0n = xp[rA]; x1n = xp[rB];
            }
        }

        // distributed h read: lane j holds h-pair j = (h[2j], h[2j+1]).
        // One conflict-free ds_read_b64 per thread; pairs are broadcast via
        // v_readlane in the dot phases (VALU, not LDS).
        const f32x2* hb2 = (const f32x2*)h_sh[s & 1];
        f32x2 hme = hb2[lane];
        const int hxb = __float_as_int(hme.x);
        const int hyb = __float_as_int(hme.y);

        // partial dot over own side's 128 cols, rows rA and rB
        f32x2 a0 = (f32x2){0.f, 0.f}, a1 = (f32x2){0.f, 0.f};
        // REG phase: pairs 0..37
#pragma unroll
        for (int j = 0; j < RP_; ++j) {
            f32x2 hj = bcast_pair(hxb, hyb, j);
            a0 = __builtin_elementwise_fma(w0[j], hj, a0);
            a1 = __builtin_elementwise_fma(w1[j], hj, a1);
        }
        // LDS phase: pairs 38..55 (one b128 each)
#pragma unroll
        for (int jj = 0; jj < LPD_; ++jj) {
            f32x2 hj = bcast_pair(hxb, hyb, RP_ + jj);
            float4 wq = Wl4[jj * 512 + t];
            a0 = __builtin_elementwise_fma((f32x2){wq.x, wq.y}, hj, a0);
            a1 = __builtin_elementwise_fma((f32x2){wq.z, wq.w}, hj, a1);
        }
        // REG-stream phase: pairs 56..63
#pragma unroll
        for (int k = 0; k < 8; ++k) {
            f32x2 hj = bcast_pair(hxb, hyb, 56 + k);
            a0 = __builtin_elementwise_fma(s0[k], hj, a0);
            a1 = __builtin_elementwise_fma(s1[k], hj, a1);
        }
        float p0 = a0.x + a0.y, p1 = a1.x + a1.y;

        const unsigned tag = (unsigned)(s + 1);
        const size_t par = (size_t)(s & 1) << 10;   // parity offset (elements)
        if (!mine) {
            unsigned long long k0 =
                ((unsigned long long)tag << 32) | (unsigned long long)__float_as_uint(p0);
            unsigned long long k1 =
                ((unsigned long long)tag << 32) | (unsigned long long)__float_as_uint(p1);
            // fast path: two plain 8B stores, same 16B line (XCD L2)
            store_l2x2(fwb + par, k0, k1);
            // slow path: LLC-coherent packed atomics (placement-safe);
            // never waited on -- producers have no per-step vmcnt waits
            unsigned long long* sb = swb + par;
            __hip_atomic_store(sb, k0, __ATOMIC_RELAXED, __HIP_MEMORY_SCOPE_AGENT);
            __hip_atomic_store(sb + 1, k1, __ATOMIC_RELAXED, __HIP_MEMORY_SCOPE_AGENT);
        } else {
            const unsigned long long* fr = frb + par;
            const unsigned long long* sr = srb + par;
            float q0f, q1f;
            for (;;) {
                unsigned long long f0, f1;
                load_l2x2(fr, f0, f1);
                if ((unsigned)(f0 >> 32) == tag && (unsigned)(f1 >> 32) == tag) {
                    q0f = __uint_as_float((unsigned)f0);
                    q1f = __uint_as_float((unsigned)f1);
                    break;
                }
                unsigned long long a0q = __hip_atomic_load(
                    sr, __ATOMIC_RELAXED, __HIP_MEMORY_SCOPE_AGENT);
                unsigned long long a1q = __hip_atomic_load(
                    sr + 1, __ATOMIC_RELAXED, __HIP_MEMORY_SCOPE_AGENT);
                if ((unsigned)(a0q >> 32) == tag && (unsigned)(a1q >> 32) == tag) {
                    q0f = __uint_as_float((unsigned)a0q);
                    q1f = __uint_as_float((unsigned)a1q);
                    break;
                }
            }
            float g0 = p0 + q0f + bias0 + x0;
            float g1 = p1 + q1f + bias1 + x1;
            // half 0: g0=i-gate, g1=g-gate; half 1: g0=f-gate, g1=o-gate
            float e0 = sigmoid_fast(g0);
            float u, v;
            if (half == 0) { u = e0 * fast_tanh(g1); v = 0.f; }  // u = i*g
            else           { u = e0; v = sigmoid_fast(g1); }     // u = f, v = o
            float fx = __shfl_xor(u, 32);   // lanes<32 receive f
            float ox = __shfl_xor(v, 32);   // lanes<32 receive o
            if (half == 0) {
                c = fx * c + u;
                float h = ox * fast_tanh(c);
                h_sh[(s + 1) & 1][(qw << 5) + li] = h;
                int orow = dir ? srow : s;
                enc[((size_t)b * S_ + orow) * 512 + dir * H_ + base + (qw << 5) + li] =
                    (orow < len) ? h : 0.f;
            }
        }
        // ONE barrier per step, LDS-only wait: h(s+1) published; no vmcnt drain
        barrier_lds();

        srow = srow_n;
        x0 = x0n; x1 = x1n;
    }
}

// ---------------------------------------------------------------------------
// K3: U = enc@Ua^T, W = enc@Wa^T
// ---------------------------------------------------------------------------
__global__ __launch_bounds__(256) void uw_kernel(
    const float* __restrict__ enc, const float* __restrict__ Ua,
    const float* __restrict__ Wa, float* __restrict__ U, float* __restrict__ Wout) {
    __shared__ float wgt[60][129];
    __shared__ float erow[4][128];
    const int tid = threadIdx.x;
    const int b = blockIdx.y, s0 = blockIdx.x * 32;
    const int rl = tid >> 6;
    const int d = tid & 63;
    const int dd = d & 31;
    const int isW = d >> 5;
    float acc[8];
#pragma unroll
    for (int i = 0; i < 8; ++i) acc[i] = 0.f;

    for (int kk = 0; kk < 4; ++kk) {
        __syncthreads();
        for (int i = tid; i < 30 * 128; i += 256) {
            int r = i >> 7, k = i & 127;
            wgt[r][k] = Ua[(size_t)r * 512 + kk * 128 + k];
            wgt[r + 30][k] = Wa[(size_t)r * 512 + kk * 128 + k];
        }
        for (int chunk = 0; chunk < 8; ++chunk) {
            __syncthreads();
            for (int i = tid; i < 4 * 128; i += 256) {
                int r = i >> 7, k = i & 127;
                erow[r][k] = enc[((size_t)b * S_ + (s0 + chunk * 4 + r)) * 512 + kk * 128 + k];
            }
            __syncthreads();
            if (dd < HID_) {
                const float* wr = wgt[dd + 30 * isW];
                const float* er = erow[rl];
                float a = acc[chunk];
#pragma unroll
                for (int k = 0; k < 128; ++k) a = fmaf(er[k], wr[k], a);
                acc[chunk] = a;
            }
        }
    }
    if (dd < HID_) {
        float* dst = isW ? Wout : U;
#pragma unroll
        for (int chunk = 0; chunk < 8; ++chunk)
            dst[((size_t)b * S_ + (s0 + chunk * 4 + rl)) * 32 + dd] = acc[chunk];
    }
}

// ---------------------------------------------------------------------------
// K4: scores + predictions
// ---------------------------------------------------------------------------
__global__ __launch_bounds__(256) void scores_kernel(
    const float* __restrict__ U, const float* __restrict__ W,
    const float* __restrict__ va,
    float* __restrict__ scores, float* __restrict__ preds) {
    __shared__ float w_sh[128][31];
    const int b = blockIdx.y, i0 = blockIdx.x * 32;
    const int tid = threadIdx.x;

    float va_r[HID_];
#pragma unroll
    for (int d2 = 0; d2 < HID_; ++d2) va_r[d2] = va[d2];

    for (int i = tid; i < 128 * HID_; i += 256) {
        int r = i / HID_, d2 = i - r * HID_;
        w_sh[r][d2] = W[((size_t)b * S_ + r) * 32 + d2];
    }
    __syncthreads();

    const int il = tid >> 3;
    const int jb = (tid & 7) * 16;
    float u_r[HID_];
    const float* urow = U + ((size_t)b * S_ + i0 + il) * 32;
#pragma unroll
    for (int d2 = 0; d2 < HID_; ++d2) u_r[d2] = urow[d2];

    const size_t obase = ((size_t)b * S_ + (i0 + il)) * S_;
    for (int jj = 0; jj < 16; ++jj) {
        int j = jb + jj;
        float acc = 0.f;
#pragma unroll
        for (int d2 = 0; d2 < HID_; ++d2)
            acc = fmaf(va_r[d2], fast_tanh(u_r[d2] + w_sh[j][d2]), acc);
        scores[obase + j] = acc;
        preds[obase + j] = (sigmoid_acc(acc) >= 0.5f) ? 1.f : 0.f;
    }
}

// ---------------------------------------------------------------------------
// Workspace layout (bytes):
//   Xg   @ 0          : 2*8192*1024*4 = 67,108,864
//   enc  @ 67,108,864 : 64*128*512*4  = 16,777,216
//   U    @ 83,886,080 : 8192*32*4     =  1,048,576
//   W    @ 84,934,656 : 8192*32*4     =  1,048,576
//   Fch  @ 85,983,232 : 128*2*2*512*8 =  2,097,152
//   Sch  @ 88,080,384 : 128*2*2*512*8 =  2,097,152
//   sT   @ 90,177,536 : 16*1024*16    =    262,144   (total ~90.4 MB)
// ---------------------------------------------------------------------------
extern "C" void kernel_launch(void* const* d_in, const int* in_sizes, int n_in,
                              void* d_out, int out_size, void* d_ws, size_t ws_size,
                              hipStream_t stream) {
    (void)in_sizes; (void)n_in; (void)out_size; (void)ws_size;
    const int* concepts = (const int*)d_in[0];
    const int* lens = (const int*)d_in[1];
    const float* embedding = (const float*)d_in[2];
    const float* Wih_f = (const float*)d_in[3];
    const float* Whh_f = (const float*)d_in[4];
    const float* b_f = (const float*)d_in[5];
    const float* Wih_b = (const float*)d_in[6];
    const float* Whh_b = (const float*)d_in[7];
    const float* b_b = (const float*)d_in[8];
    const float* Ua = (const float*)d_in[9];
    const float* Wa = (const float*)d_in[10];
    const float* va = (const float*)d_in[11];

    char* ws = (char*)d_ws;
    float* Xg = (float*)(ws + 0);
    float* enc = (float*)(ws + 67108864);
    float* U = (float*)(ws + 83886080);
    float* W = (float*)(ws + 84934656);
    unsigned long long* Fch = (unsigned long long*)(ws + 85983232);
    unsigned long long* Sch = (unsigned long long*)(ws + 88080384);
    float4* sT = (float4*)(ws + 90177536);

    float* scores = (float*)d_out;
    float* preds = scores + (size_t)B_ * S_ * S_;

    // prep folds the Fch+Sch zeroing (was hipMemsetAsync) -- one less dispatch
    hipLaunchKernelGGL(prep_stream_kernel, dim3(64), dim3(256), 0, stream,
                       Whh_f, Whh_b, sT, Fch);
    hipLaunchKernelGGL(gemm2_kernel, dim3(512, 2), dim3(256), 0, stream,
                       concepts, embedding, Wih_f, Wih_b, Xg);

    {
        const float* XgA = Xg;
        void* ka[] = {(void*)&XgA, (void*)&Whh_f, (void*)&Whh_b, (void*)&b_f,
                      (void*)&b_b, (void*)&lens, (void*)&enc, (void*)&Fch,
                      (void*)&Sch, (void*)&sT};
        (void)hipLaunchCooperativeKernel((const void*)lstm_ks3_kernel, dim3(256),
                                         dim3(512), ka,
                                         LPD_ * 512 * sizeof(float4), stream);
    }

    hipLaunchKernelGGL(uw_kernel, dim3(4, 64), dim3(256), 0, stream,
                       enc, Ua, Wa, U, W);
    hipLaunchKernelGGL(scores_kernel, dim3(4, 64), dim3(256), 0, stream,
                       U, W, va, scores, preds);
}

// Round 11
// 550.728 us; speedup vs baseline: 1.0531x; 1.0531x over previous
//
#include <hip/hip_runtime.h>

// Problem constants
#define V_  32000
#define E_  256
#define H_  256
#define S_  128
#define B_  64
#define HID_ 30

typedef float f32x2 __attribute__((ext_vector_type(2)));

// Fast activations (v_exp_f32 + v_rcp_f32; ~3e-7 abs err). Round-1/7 evidence:
// LSTM-path precision changes do not move absmax (identical 0.0004882812).
__device__ __forceinline__ float sigmoid_fast(float x) {
    return __builtin_amdgcn_rcpf(1.f + __expf(-x));
}
__device__ __forceinline__ float fast_tanh(float x) {
    return 1.f - 2.f * __builtin_amdgcn_rcpf(1.f + __expf(2.f * x));
}
__device__ __forceinline__ float sigmoid_acc(float x) {
    return 1.0f / (1.0f + expf(-x));
}

// Fast-path exchange ops (64-bit scalar operands -> VGPR pairs).
// NOTE gfx950 assembler syntax: offset: immediate must precede cache flags.
// Producer: two plain dwordx2 stores (write-through L1 -> home XCD L2).
// Consumer: two sc0 loads (L1 bypass, reads shared XCD L2), one waitcnt.
//
// POLL STRUCTURE IS LOAD-BEARING (r1, r7 post-mortems): the serial
// fast-pair-then-slow-pair loop, both checked EVERY iteration, is the only
// cadence that has not regressed. r7's higher fast-load density + early
// issue caused L2 store-starvation on the polled line (detection ~36
// iters/step, FETCH 45MB->4.9GB). Do not restructure without a
// single-variable experiment.
//
// DOT STRUCTURE NOTE (r10 post-mortem): the h-quad LDS reads are
// same-address BROADCAST reads (single access in HW) -- they are cheap.
// Replacing them with v_readlane broadcast cost +870cy/step of VALU and
// regressed 258->288us. Keep the LDS-broadcast dot.
__device__ __forceinline__ void store_l2x2(unsigned long long* p,
                                           unsigned long long a,
                                           unsigned long long b) {
    asm volatile("global_store_dwordx2 %2, %0, off\n\t"
                 "global_store_dwordx2 %2, %1, off offset:8"
                 :: "v"(a), "v"(b), "v"(p) : "memory");
}
__device__ __forceinline__ void load_l2x2(const unsigned long long* p,
                                          unsigned long long& a,
                                          unsigned long long& b) {
    asm volatile("global_load_dwordx2 %0, %2, off sc0\n\t"
                 "global_load_dwordx2 %1, %2, off offset:8 sc0\n\t"
                 "s_waitcnt vmcnt(0)"
                 : "=&v"(a), "=&v"(b) : "v"(p) : "memory");
}

// LDS-only barrier: orders LDS (h buffer) across the WG WITHOUT the vmcnt(0)
// drain __syncthreads() emits. Producers' LLC publishes / enc stores / x
// prefetches stay in flight across step boundaries.
__device__ __forceinline__ void barrier_lds() {
    asm volatile("s_waitcnt lgkmcnt(0)" ::: "memory");
    __builtin_amdgcn_s_barrier();
    __builtin_amdgcn_sched_barrier(0);
}

// ---------------------------------------------------------------------------
// K0: build sT (per (dir, side) the last 16 cols 112..127 of each Whh row,
// transposed for coalesced streaming; plane q = dir*8+side*4+j) AND zero the
// exchange channels (Fch+Sch contiguous, 4MB) -- replaces the separate
// hipMemsetAsync dispatch (tag 0 != any expected tag >= 1).
// ---------------------------------------------------------------------------
__global__ __launch_bounds__(256) void prep_stream_kernel(
    const float* __restrict__ Whh_f, const float* __restrict__ Whh_b,
    float4* __restrict__ sT, unsigned long long* __restrict__ Fch) {
    int i = blockIdx.x * 256 + threadIdx.x;      // < 16*1024
    if (i < 16 * 1024) {
        int r = i & 1023;
        int q = i >> 10;                         // 0..15
        int j = q & 3;
        int side = (q >> 2) & 1;
        int dir = q >> 3;
        const float* Whh = dir ? Whh_b : Whh_f;
        const float* src = Whh + (size_t)r * H_ + side * 128 + 112 + 4 * j;
        sT[(size_t)q * 1024 + r] = make_float4(src[0], src[1], src[2], src[3]);
    }
    // zero Fch+Sch: 2*2097152 bytes = 524288 ullongs, 16384 threads
    for (size_t k = i; k < 524288; k += 16384) Fch[k] = 0ull;
}

// ---------------------------------------------------------------------------
// K1: f32 input-projection GEMM with fused embedding gather.
// 128x128 tile, 8x8 per thread, KC=32 via LDS. grid (512, 2), block 256.
// r9-verbatim (r7/r8 "prefetch" regressed: barrier vmcnt drain voids the
// overlap and +16 VGPRs under the (256,4) budget spills).
// ---------------------------------------------------------------------------
#define GKC 32
#define GLD 132

__global__ __launch_bounds__(256, 4) void gemm2_kernel(
    const int* __restrict__ concepts, const float* __restrict__ embedding,
    const float* __restrict__ Wih_f, const float* __restrict__ Wih_b,
    float* __restrict__ Xg) {
    __shared__ float As[GKC][GLD];
    __shared__ float Bs[GKC][GLD];
    const int dir = blockIdx.y;
    const float* Wih = dir ? Wih_b : Wih_f;
    const int mt = blockIdx.x >> 3;
    const int nt = blockIdx.x & 7;
    const int m0 = mt * 128, n0 = nt * 128;
    const int t = threadIdx.x;
    const int tm = (t & 15) * 4;
    const int tn = (t >> 4) * 4;

    int cid[4], rr[4];
#pragma unroll
    for (int i = 0; i < 4; ++i) {
        int flat = t + 256 * i;
        rr[i] = flat >> 3;
        cid[i] = concepts[m0 + rr[i]];
    }

    float acc[8][8];
#pragma unroll
    for (int i = 0; i < 8; ++i)
#pragma unroll
        for (int j = 0; j < 8; ++j) acc[i][j] = 0.f;

    for (int kk = 0; kk < E_; kk += GKC) {
        __syncthreads();
#pragma unroll
        for (int i = 0; i < 4; ++i) {
            int flat = t + 256 * i;
            int r = rr[i];
            int kq = (flat & 7) * 4;
            float4 av = *(const float4*)&embedding[(size_t)cid[i] * E_ + kk + kq];
            float4 bv = *(const float4*)&Wih[(size_t)(n0 + r) * E_ + kk + kq];
            As[kq + 0][r] = av.x; As[kq + 1][r] = av.y;
            As[kq + 2][r] = av.z; As[kq + 3][r] = av.w;
            Bs[kq + 0][r] = bv.x; Bs[kq + 1][r] = bv.y;
            Bs[kq + 2][r] = bv.z; Bs[kq + 3][r] = bv.w;
        }
        __syncthreads();
#pragma unroll
        for (int k = 0; k < GKC; ++k) {
            float4 a0 = *(const float4*)&As[k][tm];
            float4 a1 = *(const float4*)&As[k][tm + 64];
            float4 b0 = *(const float4*)&Bs[k][tn];
            float4 b1 = *(const float4*)&Bs[k][tn + 64];
            float am[8] = {a0.x, a0.y, a0.z, a0.w, a1.x, a1.y, a1.z, a1.w};
            float bn[8] = {b0.x, b0.y, b0.z, b0.w, b1.x, b1.y, b1.z, b1.w};
#pragma unroll
            for (int i = 0; i < 8; ++i)
#pragma unroll
                for (int j = 0; j < 8; ++j)
                    acc[i][j] = fmaf(am[i], bn[j], acc[i][j]);
        }
    }
    float* out = Xg + ((size_t)dir * 8192 + m0) * 1024 + n0;
#pragma unroll
    for (int i = 0; i < 8; ++i) {
        int mr = (i < 4) ? (tm + i) : (tm + 60 + i);
        *(float4*)&out[(size_t)mr * 1024 + tn] =
            make_float4(acc[i][0], acc[i][1], acc[i][2], acc[i][3]);
        *(float4*)&out[(size_t)mr * 1024 + tn + 64] =
            make_float4(acc[i][4], acc[i][5], acc[i][6], acc[i][7]);
    }
}

// ---------------------------------------------------------------------------
// K2: LSTM, K-split pair with dual-path (L2-fast + LLC-safe) exchange.
// 256 WGs x 512 thr (1 WG/CU), both dirs concurrent, cooperative launch.
// w: side = w>>7 (partner = w^128), P = w&127, dir = P&1, b = P>>1.
//
// r11 single variable vs r9: producer waves run at s_setprio(1) through
// dot+publish, back to 0 after. Mechanism: with equal dots the consumer's
// poll completes at dot_end + store-visibility RTT (~300-600cy). Priority
// shifts issue slots so producers finish ~delta early / consumers ~delta
// late (same total work); step = max(T+delta, T-delta+RTT) -> hides ~RTT/2.
// r1 could not test this (confounded with SPIN-gating); producers now have
// no per-step VMEM, so the priority window is pure VALU/LDS.
//
// Weight split per thread (2 rows rA,rB over the side's 128 cols = 64 pairs):
//   pairs  0..37 : registers (asm-pinned), pairs 38..55 : LDS float4-interleaved,
//   pairs 56..63 : registers (loop-invariant, hoisted). Producers have no
//   per-step VMEM loads.
// Row mapping (intra-wave gate pairing): wave=t>>6, lane=t&63, li=lane&31,
// half=lane>>5, qw=(wave&1)|((wave>>2)<<1), consumer iff ((wave>>1)&1)==side.
// hcol=128*hs+32*qw+li; rA=hcol+half*256; rB=rA+512. f,o handoff =
// __shfl_xor(.,32). ONE LDS-only barrier/step, h double-buffered.
// Poll: r6-verbatim serial dual-path (see note at store_l2x2).
// ---------------------------------------------------------------------------
#define RP_  38
#define LPD_ 18

__global__ __launch_bounds__(512)
__attribute__((amdgpu_waves_per_eu(2, 2)))
void lstm_ks3_kernel(
    const float* __restrict__ Xg,     // [2][8192][1024]
    const float* __restrict__ Whh_f, const float* __restrict__ Whh_b,
    const float* __restrict__ b_f, const float* __restrict__ b_b,
    const int* __restrict__ lens,
    float* __restrict__ enc,          // [B][S][512]
    unsigned long long* __restrict__ Fch,  // [P=128][2 par][2 prodside][512]
    unsigned long long* __restrict__ Sch,  // [P=128][2 par][2 prodside][512]
    const float4* __restrict__ sT) {  // [16][1024]
    extern __shared__ float4 Wl4[];   // [LPD_][512]
    __shared__ float h_sh[2][128];    // double-buffered own-side h (read s&1)
    const int w = blockIdx.x;
    const int side = w >> 7;
    const int P = w & 127;
    const int dir = P & 1, b = P >> 1;
    const int t = threadIdx.x;
    const int wav = t >> 6;
    const int lane = t & 63;
    const int li = lane & 31;
    const int half = lane >> 5;                    // 0:(i,g)  1:(f,o)
    const int qw = (wav & 1) | ((wav >> 2) << 1);  // 0..3 within cons/prod set
    const bool mine = (((wav >> 1) & 1) == side);  // consumer wave (uniform)
    const int hs = mine ? side : (side ^ 1);       // side of h-cols served
    const int hcol = (hs << 7) + (qw << 5) + li;   // h column 0..255
    const int rA = hcol + half * 256;              // i- or f-gate row
    const int rB = hcol + 512 + half * 256;        // g- or o-gate row
    const int base = side << 7;
    const int idx = (qw << 6) + lane;              // exchange slot 0..255
    const float* Whh = dir ? Whh_b : Whh_f;
    const int len = lens[b];

    // pin weights: rows rA, rB, own-side pair-cols [0,38) in regs
    f32x2 w0[RP_], w1[RP_];
    {
        const f32x2* p0 = (const f32x2*)(Whh + (size_t)rA * H_ + base);
        const f32x2* p1 = (const f32x2*)(Whh + (size_t)rB * H_ + base);
#pragma unroll
        for (int j = 0; j < RP_; ++j) { w0[j] = p0[j]; w1[j] = p1[j]; }
        // pairs [38,56) in LDS, rA/rB interleaved -> one b128 per pair
#pragma unroll
        for (int j = 0; j < LPD_; ++j) {
            f32x2 a = p0[RP_ + j], c2 = p1[RP_ + j];
            Wl4[j * 512 + t] = make_float4(a.x, a.y, c2.x, c2.y);
        }
    }
    // pairs 56..63: loop-invariant, pinned in regs as f32x2 (8 per row)
    const f32x2* sT2 = (const f32x2*)(sT + (size_t)(dir * 8 + side * 4) * 1024);
    f32x2 s0[8], s1[8];
#pragma unroll
    for (int k = 0; k < 4; ++k) {
        s0[2 * k]     = sT2[2 * (k * 1024 + rA)];
        s0[2 * k + 1] = sT2[2 * (k * 1024 + rA) + 1];
        s1[2 * k]     = sT2[2 * (k * 1024 + rB)];
        s1[2 * k + 1] = sT2[2 * (k * 1024 + rB) + 1];
    }
    // Keep pinned values live in the register file across the whole loop.
    // NOTE: 64-bit f32x2 ties compile; 128-bit float4 ties do not (r5).
#pragma unroll
    for (int j = 0; j < RP_; ++j) {
        asm volatile("" : "+v"(w0[j]), "+v"(w1[j]));
    }
#pragma unroll
    for (int k = 0; k < 8; ++k) {
        asm volatile("" : "+v"(s0[k]), "+v"(s1[k]));
    }
    const float* bias = dir ? b_b : b_f;
    const float bias0 = bias[rA], bias1 = bias[rB];

    // exchange base pointers (parity applied per step via +1024 elements)
    unsigned long long* fwb = Fch + (((size_t)P * 2 + 0) * 2 + side) * 512 + 2 * idx;
    const unsigned long long* frb =
        Fch + (((size_t)P * 2 + 0) * 2 + (side ^ 1)) * 512 + 2 * idx;
    unsigned long long* swb = Sch + (((size_t)P * 2 + 0) * 2 + side) * 512 + 2 * idx;
    const unsigned long long* srb =
        Sch + (((size_t)P * 2 + 0) * 2 + (side ^ 1)) * 512 + 2 * idx;

    if (t < 128) h_sh[0][t] = 0.f;
    float c = 0.f;                    // cell state (consumer lanes 0..31)
    __syncthreads();                  // full sync once (Wl4 + h init)

    // x prefetch (consumers only)
    int srow = dir ? (len - 1) : 0;   // len >= 1 guaranteed
    float x0 = 0.f, x1 = 0.f;
    if (mine) {
        const float* xp = Xg + ((size_t)dir * 8192 + (size_t)srow * B_ + b) * 1024;
        x0 = xp[rA]; x1 = xp[rB];
    }

    for (int s = 0; s < S_; ++s) {
        // next-step x prefetch
        int srow_n = 0;
        float x0n = 0.f, x1n = 0.f;
        if (s + 1 < S_) {
            int ns = s + 1;
            srow_n = dir ? ((ns < len) ? (len - 1 - ns) : ns) : ns;
            if (mine) {
                const float* xp =
                    Xg + ((size_t)dir * 8192 + (size_t)srow_n * B_ + b) * 1024;
                x0n = xp[rA]; x1n = xp[rB];
            }
        }

        // r11: producer waves run hot through dot+publish so the partial
        // becomes visible before the (deprioritized) consumer finishes its
        // own dot -- hides ~RTT/2 of the detect latency.
        if (!mine) __builtin_amdgcn_s_setprio(1);

        // partial dot over own side's 128 cols, rows rA and rB
        const float4* hb4 = (const float4*)h_sh[s & 1];
        f32x2 a0 = (f32x2){0.f, 0.f}, a1 = (f32x2){0.f, 0.f};
        // REG phase: pairs 0..37, h quads 0..18
#pragma unroll
        for (int q = 0; q < 19; ++q) {
            float4 hq = hb4[q];
            f32x2 hA = (f32x2){hq.x, hq.y}, hB = (f32x2){hq.z, hq.w};
            a0 = __builtin_elementwise_fma(w0[2 * q], hA, a0);
            a0 = __builtin_elementwise_fma(w0[2 * q + 1], hB, a0);
            a1 = __builtin_elementwise_fma(w1[2 * q], hA, a1);
            a1 = __builtin_elementwise_fma(w1[2 * q + 1], hB, a1);
        }
        // LDS phase: pairs 38..55 (one b128 each), h quads 19..27
#pragma unroll
        for (int jj = 0; jj < 9; ++jj) {
            float4 hq = hb4[19 + jj];
            f32x2 hA = (f32x2){hq.x, hq.y}, hB = (f32x2){hq.z, hq.w};
            float4 wE = Wl4[(2 * jj) * 512 + t];       // pair 38+2jj
            float4 wO = Wl4[(2 * jj + 1) * 512 + t];   // pair 39+2jj
            a0 = __builtin_elementwise_fma((f32x2){wE.x, wE.y}, hA, a0);
            a1 = __builtin_elementwise_fma((f32x2){wE.z, wE.w}, hA, a1);
            a0 = __builtin_elementwise_fma((f32x2){wO.x, wO.y}, hB, a0);
            a1 = __builtin_elementwise_fma((f32x2){wO.z, wO.w}, hB, a1);
        }
        // REG-stream phase: pairs 56..63, h quads 28..31
#pragma unroll
        for (int k = 0; k < 4; ++k) {
            float4 hq = hb4[28 + k];
            f32x2 hA = (f32x2){hq.x, hq.y}, hB = (f32x2){hq.z, hq.w};
            a0 = __builtin_elementwise_fma(s0[2 * k], hA, a0);
            a0 = __builtin_elementwise_fma(s0[2 * k + 1], hB, a0);
            a1 = __builtin_elementwise_fma(s1[2 * k], hA, a1);
            a1 = __builtin_elementwise_fma(s1[2 * k + 1], hB, a1);
        }
        float p0 = a0.x + a0.y, p1 = a1.x + a1.y;

        const unsigned tag = (unsigned)(s + 1);
        const size_t par = (size_t)(s & 1) << 10;   // parity offset (elements)
        if (!mine) {
            unsigned long long k0 =
                ((unsigned long long)tag << 32) | (unsigned long long)__float_as_uint(p0);
            unsigned long long k1 =
                ((unsigned long long)tag << 32) | (unsigned long long)__float_as_uint(p1);
            // fast path: two plain 8B stores, same 16B line (XCD L2)
            store_l2x2(fwb + par, k0, k1);
            // slow path: LLC-coherent packed atomics (placement-safe);
            // never waited on -- producers have no per-step vmcnt waits
            unsigned long long* sb = swb + par;
            __hip_atomic_store(sb, k0, __ATOMIC_RELAXED, __HIP_MEMORY_SCOPE_AGENT);
            __hip_atomic_store(sb + 1, k1, __ATOMIC_RELAXED, __HIP_MEMORY_SCOPE_AGENT);
            __builtin_amdgcn_s_setprio(0);   // publish done, back to normal
        } else {
            const unsigned long long* fr = frb + par;
            const unsigned long long* sr = srb + par;
            float q0f, q1f;
            for (;;) {
                unsigned long long f0, f1;
                load_l2x2(fr, f0, f1);
                if ((unsigned)(f0 >> 32) == tag && (unsigned)(f1 >> 32) == tag) {
                    q0f = __uint_as_float((unsigned)f0);
                    q1f = __uint_as_float((unsigned)f1);
                    break;
                }
                unsigned long long a0q = __hip_atomic_load(
                    sr, __ATOMIC_RELAXED, __HIP_MEMORY_SCOPE_AGENT);
                unsigned long long a1q = __hip_atomic_load(
                    sr + 1, __ATOMIC_RELAXED, __HIP_MEMORY_SCOPE_AGENT);
                if ((unsigned)(a0q >> 32) == tag && (unsigned)(a1q >> 32) == tag) {
                    q0f = __uint_as_float((unsigned)a0q);
                    q1f = __uint_as_float((unsigned)a1q);
                    break;
                }
            }
            float g0 = p0 + q0f + bias0 + x0;
            float g1 = p1 + q1f + bias1 + x1;
            // half 0: g0=i-gate, g1=g-gate; half 1: g0=f-gate, g1=o-gate
            float e0 = sigmoid_fast(g0);
            float u, v;
            if (half == 0) { u = e0 * fast_tanh(g1); v = 0.f; }  // u = i*g
            else           { u = e0; v = sigmoid_fast(g1); }     // u = f, v = o
            float fx = __shfl_xor(u, 32);   // lanes<32 receive f
            float ox = __shfl_xor(v, 32);   // lanes<32 receive o
            if (half == 0) {
                c = fx * c + u;
                float h = ox * fast_tanh(c);
                h_sh[(s + 1) & 1][(qw << 5) + li] = h;
                int orow = dir ? srow : s;
                enc[((size_t)b * S_ + orow) * 512 + dir * H_ + base + (qw << 5) + li] =
                    (orow < len) ? h : 0.f;
            }
        }
        // ONE barrier per step, LDS-only wait: h(s+1) published; no vmcnt drain
        barrier_lds();

        srow = srow_n;
        x0 = x0n; x1 = x1n;
    }
}

// ---------------------------------------------------------------------------
// K3: U = enc@Ua^T, W = enc@Wa^T
// ---------------------------------------------------------------------------
__global__ __launch_bounds__(256) void uw_kernel(
    const float* __restrict__ enc, const float* __restrict__ Ua,
    const float* __restrict__ Wa, float* __restrict__ U, float* __restrict__ Wout) {
    __shared__ float wgt[60][129];
    __shared__ float erow[4][128];
    const int tid = threadIdx.x;
    const int b = blockIdx.y, s0 = blockIdx.x * 32;
    const int rl = tid >> 6;
    const int d = tid & 63;
    const int dd = d & 31;
    const int isW = d >> 5;
    float acc[8];
#pragma unroll
    for (int i = 0; i < 8; ++i) acc[i] = 0.f;

    for (int kk = 0; kk < 4; ++kk) {
        __syncthreads();
        for (int i = tid; i < 30 * 128; i += 256) {
            int r = i >> 7, k = i & 127;
            wgt[r][k] = Ua[(size_t)r * 512 + kk * 128 + k];
            wgt[r + 30][k] = Wa[(size_t)r * 512 + kk * 128 + k];
        }
        for (int chunk = 0; chunk < 8; ++chunk) {
            __syncthreads();
            for (int i = tid; i < 4 * 128; i += 256) {
                int r = i >> 7, k = i & 127;
                erow[r][k] = enc[((size_t)b * S_ + (s0 + chunk * 4 + r)) * 512 + kk * 128 + k];
            }
            __syncthreads();
            if (dd < HID_) {
                const float* wr = wgt[dd + 30 * isW];
                const float* er = erow[rl];
                float a = acc[chunk];
#pragma unroll
                for (int k = 0; k < 128; ++k) a = fmaf(er[k], wr[k], a);
                acc[chunk] = a;
            }
        }
    }
    if (dd < HID_) {
        float* dst = isW ? Wout : U;
#pragma unroll
        for (int chunk = 0; chunk < 8; ++chunk)
            dst[((size_t)b * S_ + (s0 + chunk * 4 + rl)) * 32 + dd] = acc[chunk];
    }
}

// ---------------------------------------------------------------------------
// K4: scores + predictions
// ---------------------------------------------------------------------------
__global__ __launch_bounds__(256) void scores_kernel(
    const float* __restrict__ U, const float* __restrict__ W,
    const float* __restrict__ va,
    float* __restrict__ scores, float* __restrict__ preds) {
    __shared__ float w_sh[128][31];
    const int b = blockIdx.y, i0 = blockIdx.x * 32;
    const int tid = threadIdx.x;

    float va_r[HID_];
#pragma unroll
    for (int d2 = 0; d2 < HID_; ++d2) va_r[d2] = va[d2];

    for (int i = tid; i < 128 * HID_; i += 256) {
        int r = i / HID_, d2 = i - r * HID_;
        w_sh[r][d2] = W[((size_t)b * S_ + r) * 32 + d2];
    }
    __syncthreads();

    const int il = tid >> 3;
    const int jb = (tid & 7) * 16;
    float u_r[HID_];
    const float* urow = U + ((size_t)b * S_ + i0 + il) * 32;
#pragma unroll
    for (int d2 = 0; d2 < HID_; ++d2) u_r[d2] = urow[d2];

    const size_t obase = ((size_t)b * S_ + (i0 + il)) * S_;
    for (int jj = 0; jj < 16; ++jj) {
        int j = jb + jj;
        float acc = 0.f;
#pragma unroll
        for (int d2 = 0; d2 < HID_; ++d2)
            acc = fmaf(va_r[d2], fast_tanh(u_r[d2] + w_sh[j][d2]), acc);
        scores[obase + j] = acc;
        preds[obase + j] = (sigmoid_acc(acc) >= 0.5f) ? 1.f : 0.f;
    }
}

// ---------------------------------------------------------------------------
// Workspace layout (bytes):
//   Xg   @ 0          : 2*8192*1024*4 = 67,108,864
//   enc  @ 67,108,864 : 64*128*512*4  = 16,777,216
//   U    @ 83,886,080 : 8192*32*4     =  1,048,576
//   W    @ 84,934,656 : 8192*32*4     =  1,048,576
//   Fch  @ 85,983,232 : 128*2*2*512*8 =  2,097,152
//   Sch  @ 88,080,384 : 128*2*2*512*8 =  2,097,152
//   sT   @ 90,177,536 : 16*1024*16    =    262,144   (total ~90.4 MB)
// ---------------------------------------------------------------------------
extern "C" void kernel_launch(void* const* d_in, const int* in_sizes, int n_in,
                              void* d_out, int out_size, void* d_ws, size_t ws_size,
                              hipStream_t stream) {
    (void)in_sizes; (void)n_in; (void)out_size; (void)ws_size;
    const int* concepts = (const int*)d_in[0];
    const int* lens = (const int*)d_in[1];
    const float* embedding = (const float*)d_in[2];
    const float* Wih_f = (const float*)d_in[3];
    const float* Whh_f = (const float*)d_in[4];
    const float* b_f = (const float*)d_in[5];
    const float* Wih_b = (const float*)d_in[6];
    const float* Whh_b = (const float*)d_in[7];
    const float* b_b = (const float*)d_in[8];
    const float* Ua = (const float*)d_in[9];
    const float* Wa = (const float*)d_in[10];
    const float* va = (const float*)d_in[11];

    char* ws = (char*)d_ws;
    float* Xg = (float*)(ws + 0);
    float* enc = (float*)(ws + 67108864);
    float* U = (float*)(ws + 83886080);
    float* W = (float*)(ws + 84934656);
    unsigned long long* Fch = (unsigned long long*)(ws + 85983232);
    unsigned long long* Sch = (unsigned long long*)(ws + 88080384);
    float4* sT = (float4*)(ws + 90177536);

    float* scores = (float*)d_out;
    float* preds = scores + (size_t)B_ * S_ * S_;

    // prep folds the Fch+Sch zeroing (was hipMemsetAsync) -- one less dispatch
    hipLaunchKernelGGL(prep_stream_kernel, dim3(64), dim3(256), 0, stream,
                       Whh_f, Whh_b, sT, Fch);
    hipLaunchKernelGGL(gemm2_kernel, dim3(512, 2), dim3(256), 0, stream,
                       concepts, embedding, Wih_f, Wih_b, Xg);

    {
        const float* XgA = Xg;
        void* ka[] = {(void*)&XgA, (void*)&Whh_f, (void*)&Whh_b, (void*)&b_f,
                      (void*)&b_b, (void*)&lens, (void*)&enc, (void*)&Fch,
                      (void*)&Sch, (void*)&sT};
        (void)hipLaunchCooperativeKernel((const void*)lstm_ks3_kernel, dim3(256),
                                         dim3(512), ka,
                                         LPD_ * 512 * sizeof(float4), stream);
    }

    hipLaunchKernelGGL(uw_kernel, dim3(4, 64), dim3(256), 0, stream,
                       enc, Ua, Wa, U, W);
    hipLaunchKernelGGL(scores_kernel, dim3(4, 64), dim3(256), 0, stream,
                       U, W, va, scores, preds);
}

// Round 12
// 531.319 us; speedup vs baseline: 1.0916x; 1.0365x over previous
//
#include <hip/hip_runtime.h>

// Problem constants
#define V_  32000
#define E_  256
#define H_  256
#define S_  128
#define B_  64
#define HID_ 30

typedef float f32x2 __attribute__((ext_vector_type(2)));

// Fast activations (v_exp_f32 + v_rcp_f32; ~3e-7 abs err). Round-1/7 evidence:
// LSTM-path precision changes do not move absmax (identical 0.0004882812).
__device__ __forceinline__ float sigmoid_fast(float x) {
    return __builtin_amdgcn_rcpf(1.f + __expf(-x));
}
__device__ __forceinline__ float fast_tanh(float x) {
    return 1.f - 2.f * __builtin_amdgcn_rcpf(1.f + __expf(2.f * x));
}
__device__ __forceinline__ float sigmoid_acc(float x) {
    return 1.0f / (1.0f + expf(-x));
}

// Fast-path exchange ops (64-bit scalar operands -> VGPR pairs).
// NOTE gfx950 assembler syntax: offset: immediate must precede cache flags.
// Producer: two plain dwordx2 stores (write-through L1 -> home XCD L2).
// Consumer: two sc0 loads (L1 bypass, reads shared XCD L2), one waitcnt.
//
// POLL STRUCTURE IS LOAD-BEARING (r1, r7 post-mortems): the serial
// fast-pair-then-slow-pair loop, both checked EVERY iteration, is the only
// cadence that has not regressed. r7's higher fast-load density + early
// issue caused L2 store-starvation on the polled line. Do not restructure.
//
// DOT STRUCTURE NOTE (r10): h-quad LDS reads are same-address BROADCAST
// reads (single access in HW) -- cheap. v_readlane broadcast regressed.
// SETPRIO NOTE (r11): producer s_setprio(1) measured NEUTRAL; removed.
__device__ __forceinline__ void store_l2x2(unsigned long long* p,
                                           unsigned long long a,
                                           unsigned long long b) {
    asm volatile("global_store_dwordx2 %2, %0, off\n\t"
                 "global_store_dwordx2 %2, %1, off offset:8"
                 :: "v"(a), "v"(b), "v"(p) : "memory");
}
__device__ __forceinline__ void load_l2x2(const unsigned long long* p,
                                          unsigned long long& a,
                                          unsigned long long& b) {
    asm volatile("global_load_dwordx2 %0, %2, off sc0\n\t"
                 "global_load_dwordx2 %1, %2, off offset:8 sc0\n\t"
                 "s_waitcnt vmcnt(0)"
                 : "=&v"(a), "=&v"(b) : "v"(p) : "memory");
}

// LDS-only barrier: orders LDS (h buffer) across the WG WITHOUT the vmcnt(0)
// drain __syncthreads() emits.
__device__ __forceinline__ void barrier_lds() {
    asm volatile("s_waitcnt lgkmcnt(0)" ::: "memory");
    __builtin_amdgcn_s_barrier();
    __builtin_amdgcn_sched_barrier(0);
}

// ---------------------------------------------------------------------------
// K0: build sT (per (dir, side) the last 16 cols 112..127 of each Whh row,
// transposed; plane q = dir*8+side*4+j) AND zero the exchange channels
// (Fch+Sch contiguous, 4MB) -- replaces the hipMemsetAsync dispatch.
// ---------------------------------------------------------------------------
__global__ __launch_bounds__(256) void prep_stream_kernel(
    const float* __restrict__ Whh_f, const float* __restrict__ Whh_b,
    float4* __restrict__ sT, unsigned long long* __restrict__ Fch) {
    int i = blockIdx.x * 256 + threadIdx.x;      // < 16*1024
    if (i < 16 * 1024) {
        int r = i & 1023;
        int q = i >> 10;                         // 0..15
        int j = q & 3;
        int side = (q >> 2) & 1;
        int dir = q >> 3;
        const float* Whh = dir ? Whh_b : Whh_f;
        const float* src = Whh + (size_t)r * H_ + side * 128 + 112 + 4 * j;
        sT[(size_t)q * 1024 + r] = make_float4(src[0], src[1], src[2], src[3]);
    }
    // zero Fch+Sch: 2*2097152 bytes = 524288 ullongs, 16384 threads
    for (size_t k = i; k < 524288; k += 16384) Fch[k] = 0ull;
}

// ---------------------------------------------------------------------------
// K1: f32 input-projection GEMM with fused embedding gather.
// 128x128 tile, 8x8 per thread, KC=32 via LDS. grid (512, 2), block 256.
// r12: inner loop uses f32x2 packed FMA (v_pk_fma_f32) -- 32 pk insts per
// K-step instead of 64 scalar. Identical math/rounding (same FMA ops).
// Rate experiment: full-rate pk halves gemm2's 62us FMA-issue floor.
// ---------------------------------------------------------------------------
#define GKC 32
#define GLD 132

__global__ __launch_bounds__(256, 4) void gemm2_kernel(
    const int* __restrict__ concepts, const float* __restrict__ embedding,
    const float* __restrict__ Wih_f, const float* __restrict__ Wih_b,
    float* __restrict__ Xg) {
    __shared__ float As[GKC][GLD];
    __shared__ float Bs[GKC][GLD];
    const int dir = blockIdx.y;
    const float* Wih = dir ? Wih_b : Wih_f;
    const int mt = blockIdx.x >> 3;
    const int nt = blockIdx.x & 7;
    const int m0 = mt * 128, n0 = nt * 128;
    const int t = threadIdx.x;
    const int tm = (t & 15) * 4;
    const int tn = (t >> 4) * 4;

    int cid[4], rr[4];
#pragma unroll
    for (int i = 0; i < 4; ++i) {
        int flat = t + 256 * i;
        rr[i] = flat >> 3;
        cid[i] = concepts[m0 + rr[i]];
    }

    f32x2 acc2[8][4];
#pragma unroll
    for (int i = 0; i < 8; ++i)
#pragma unroll
        for (int j = 0; j < 4; ++j) acc2[i][j] = (f32x2){0.f, 0.f};

    for (int kk = 0; kk < E_; kk += GKC) {
        __syncthreads();
#pragma unroll
        for (int i = 0; i < 4; ++i) {
            int flat = t + 256 * i;
            int r = rr[i];
            int kq = (flat & 7) * 4;
            float4 av = *(const float4*)&embedding[(size_t)cid[i] * E_ + kk + kq];
            float4 bv = *(const float4*)&Wih[(size_t)(n0 + r) * E_ + kk + kq];
            As[kq + 0][r] = av.x; As[kq + 1][r] = av.y;
            As[kq + 2][r] = av.z; As[kq + 3][r] = av.w;
            Bs[kq + 0][r] = bv.x; Bs[kq + 1][r] = bv.y;
            Bs[kq + 2][r] = bv.z; Bs[kq + 3][r] = bv.w;
        }
        __syncthreads();
#pragma unroll
        for (int k = 0; k < GKC; ++k) {
            float4 a0 = *(const float4*)&As[k][tm];
            float4 a1 = *(const float4*)&As[k][tm + 64];
            float4 b0 = *(const float4*)&Bs[k][tn];
            float4 b1 = *(const float4*)&Bs[k][tn + 64];
            float am[8] = {a0.x, a0.y, a0.z, a0.w, a1.x, a1.y, a1.z, a1.w};
            f32x2 bn2[4] = {(f32x2){b0.x, b0.y}, (f32x2){b0.z, b0.w},
                            (f32x2){b1.x, b1.y}, (f32x2){b1.z, b1.w}};
#pragma unroll
            for (int i = 0; i < 8; ++i) {
                f32x2 ai = (f32x2){am[i], am[i]};
#pragma unroll
                for (int j = 0; j < 4; ++j)
                    acc2[i][j] = __builtin_elementwise_fma(ai, bn2[j], acc2[i][j]);
            }
        }
    }
    float* out = Xg + ((size_t)dir * 8192 + m0) * 1024 + n0;
#pragma unroll
    for (int i = 0; i < 8; ++i) {
        int mr = (i < 4) ? (tm + i) : (tm + 60 + i);
        *(float4*)&out[(size_t)mr * 1024 + tn] =
            make_float4(acc2[i][0].x, acc2[i][0].y, acc2[i][1].x, acc2[i][1].y);
        *(float4*)&out[(size_t)mr * 1024 + tn + 64] =
            make_float4(acc2[i][2].x, acc2[i][2].y, acc2[i][3].x, acc2[i][3].y);
    }
}

// ---------------------------------------------------------------------------
// K2: LSTM, K-split pair with dual-path (L2-fast + LLC-safe) exchange.
// 256 WGs x 512 thr (1 WG/CU), both dirs concurrent, cooperative launch.
// r9-EXACT (best measured: 257.4-258.6us; r11 setprio was neutral, removed).
//
// Weight split per thread (2 rows rA,rB over the side's 128 cols = 64 pairs):
//   pairs  0..37 : registers (asm-pinned), pairs 38..55 : LDS float4-interleaved,
//   pairs 56..63 : registers (loop-invariant, hoisted). Producers have no
//   per-step VMEM loads.
// Row mapping (intra-wave gate pairing): wave=t>>6, lane=t&63, li=lane&31,
// half=lane>>5, qw=(wave&1)|((wave>>2)<<1), consumer iff ((wave>>1)&1)==side.
// hcol=128*hs+32*qw+li; rA=hcol+half*256; rB=rA+512. f,o handoff =
// __shfl_xor(.,32). ONE LDS-only barrier/step, h double-buffered.
// Poll: r6-verbatim serial dual-path (see note at store_l2x2).
// ---------------------------------------------------------------------------
#define RP_  38
#define LPD_ 18

__global__ __launch_bounds__(512)
__attribute__((amdgpu_waves_per_eu(2, 2)))
void lstm_ks3_kernel(
    const float* __restrict__ Xg,     // [2][8192][1024]
    const float* __restrict__ Whh_f, const float* __restrict__ Whh_b,
    const float* __restrict__ b_f, const float* __restrict__ b_b,
    const int* __restrict__ lens,
    float* __restrict__ enc,          // [B][S][512]
    unsigned long long* __restrict__ Fch,  // [P=128][2 par][2 prodside][512]
    unsigned long long* __restrict__ Sch,  // [P=128][2 par][2 prodside][512]
    const float4* __restrict__ sT) {  // [16][1024]
    extern __shared__ float4 Wl4[];   // [LPD_][512]
    __shared__ float h_sh[2][128];    // double-buffered own-side h (read s&1)
    const int w = blockIdx.x;
    const int side = w >> 7;
    const int P = w & 127;
    const int dir = P & 1, b = P >> 1;
    const int t = threadIdx.x;
    const int wav = t >> 6;
    const int lane = t & 63;
    const int li = lane & 31;
    const int half = lane >> 5;                    // 0:(i,g)  1:(f,o)
    const int qw = (wav & 1) | ((wav >> 2) << 1);  // 0..3 within cons/prod set
    const bool mine = (((wav >> 1) & 1) == side);  // consumer wave (uniform)
    const int hs = mine ? side : (side ^ 1);       // side of h-cols served
    const int hcol = (hs << 7) + (qw << 5) + li;   // h column 0..255
    const int rA = hcol + half * 256;              // i- or f-gate row
    const int rB = hcol + 512 + half * 256;        // g- or o-gate row
    const int base = side << 7;
    const int idx = (qw << 6) + lane;              // exchange slot 0..255
    const float* Whh = dir ? Whh_b : Whh_f;
    const int len = lens[b];

    // pin weights: rows rA, rB, own-side pair-cols [0,38) in regs
    f32x2 w0[RP_], w1[RP_];
    {
        const f32x2* p0 = (const f32x2*)(Whh + (size_t)rA * H_ + base);
        const f32x2* p1 = (const f32x2*)(Whh + (size_t)rB * H_ + base);
#pragma unroll
        for (int j = 0; j < RP_; ++j) { w0[j] = p0[j]; w1[j] = p1[j]; }
        // pairs [38,56) in LDS, rA/rB interleaved -> one b128 per pair
#pragma unroll
        for (int j = 0; j < LPD_; ++j) {
            f32x2 a = p0[RP_ + j], c2 = p1[RP_ + j];
            Wl4[j * 512 + t] = make_float4(a.x, a.y, c2.x, c2.y);
        }
    }
    // pairs 56..63: loop-invariant, pinned in regs as f32x2 (8 per row)
    const f32x2* sT2 = (const f32x2*)(sT + (size_t)(dir * 8 + side * 4) * 1024);
    f32x2 s0[8], s1[8];
#pragma unroll
    for (int k = 0; k < 4; ++k) {
        s0[2 * k]     = sT2[2 * (k * 1024 + rA)];
        s0[2 * k + 1] = sT2[2 * (k * 1024 + rA) + 1];
        s1[2 * k]     = sT2[2 * (k * 1024 + rB)];
        s1[2 * k + 1] = sT2[2 * (k * 1024 + rB) + 1];
    }
    // Keep pinned values live in the register file across the whole loop.
    // NOTE: 64-bit f32x2 ties compile; 128-bit float4 ties do not (r5).
#pragma unroll
    for (int j = 0; j < RP_; ++j) {
        asm volatile("" : "+v"(w0[j]), "+v"(w1[j]));
    }
#pragma unroll
    for (int k = 0; k < 8; ++k) {
        asm volatile("" : "+v"(s0[k]), "+v"(s1[k]));
    }
    const float* bias = dir ? b_b : b_f;
    const float bias0 = bias[rA], bias1 = bias[rB];

    // exchange base pointers (parity applied per step via +1024 elements)
    unsigned long long* fwb = Fch + (((size_t)P * 2 + 0) * 2 + side) * 512 + 2 * idx;
    const unsigned long long* frb =
        Fch + (((size_t)P * 2 + 0) * 2 + (side ^ 1)) * 512 + 2 * idx;
    unsigned long long* swb = Sch + (((size_t)P * 2 + 0) * 2 + side) * 512 + 2 * idx;
    const unsigned long long* srb =
        Sch + (((size_t)P * 2 + 0) * 2 + (side ^ 1)) * 512 + 2 * idx;

    if (t < 128) h_sh[0][t] = 0.f;
    float c = 0.f;                    // cell state (consumer lanes 0..31)
    __syncthreads();                  // full sync once (Wl4 + h init)

    // x prefetch (consumers only)
    int srow = dir ? (len - 1) : 0;   // len >= 1 guaranteed
    float x0 = 0.f, x1 = 0.f;
    if (mine) {
        const float* xp = Xg + ((size_t)dir * 8192 + (size_t)srow * B_ + b) * 1024;
        x0 = xp[rA]; x1 = xp[rB];
    }

    for (int s = 0; s < S_; ++s) {
        // next-step x prefetch
        int srow_n = 0;
        float x0n = 0.f, x1n = 0.f;
        if (s + 1 < S_) {
            int ns = s + 1;
            srow_n = dir ? ((ns < len) ? (len - 1 - ns) : ns) : ns;
            if (mine) {
                const float* xp =
                    Xg + ((size_t)dir * 8192 + (size_t)srow_n * B_ + b) * 1024;
                x0n = xp[rA]; x1n = xp[rB];
            }
        }

        // partial dot over own side's 128 cols, rows rA and rB
        const float4* hb4 = (const float4*)h_sh[s & 1];
        f32x2 a0 = (f32x2){0.f, 0.f}, a1 = (f32x2){0.f, 0.f};
        // REG phase: pairs 0..37, h quads 0..18
#pragma unroll
        for (int q = 0; q < 19; ++q) {
            float4 hq = hb4[q];
            f32x2 hA = (f32x2){hq.x, hq.y}, hB = (f32x2){hq.z, hq.w};
            a0 = __builtin_elementwise_fma(w0[2 * q], hA, a0);
            a0 = __builtin_elementwise_fma(w0[2 * q + 1], hB, a0);
            a1 = __builtin_elementwise_fma(w1[2 * q], hA, a1);
            a1 = __builtin_elementwise_fma(w1[2 * q + 1], hB, a1);
        }
        // LDS phase: pairs 38..55 (one b128 each), h quads 19..27
#pragma unroll
        for (int jj = 0; jj < 9; ++jj) {
            float4 hq = hb4[19 + jj];
            f32x2 hA = (f32x2){hq.x, hq.y}, hB = (f32x2){hq.z, hq.w};
            float4 wE = Wl4[(2 * jj) * 512 + t];       // pair 38+2jj
            float4 wO = Wl4[(2 * jj + 1) * 512 + t];   // pair 39+2jj
            a0 = __builtin_elementwise_fma((f32x2){wE.x, wE.y}, hA, a0);
            a1 = __builtin_elementwise_fma((f32x2){wE.z, wE.w}, hA, a1);
            a0 = __builtin_elementwise_fma((f32x2){wO.x, wO.y}, hB, a0);
            a1 = __builtin_elementwise_fma((f32x2){wO.z, wO.w}, hB, a1);
        }
        // REG-stream phase: pairs 56..63, h quads 28..31
#pragma unroll
        for (int k = 0; k < 4; ++k) {
            float4 hq = hb4[28 + k];
            f32x2 hA = (f32x2){hq.x, hq.y}, hB = (f32x2){hq.z, hq.w};
            a0 = __builtin_elementwise_fma(s0[2 * k], hA, a0);
            a0 = __builtin_elementwise_fma(s0[2 * k + 1], hB, a0);
            a1 = __builtin_elementwise_fma(s1[2 * k], hA, a1);
            a1 = __builtin_elementwise_fma(s1[2 * k + 1], hB, a1);
        }
        float p0 = a0.x + a0.y, p1 = a1.x + a1.y;

        const unsigned tag = (unsigned)(s + 1);
        const size_t par = (size_t)(s & 1) << 10;   // parity offset (elements)
        if (!mine) {
            unsigned long long k0 =
                ((unsigned long long)tag << 32) | (unsigned long long)__float_as_uint(p0);
            unsigned long long k1 =
                ((unsigned long long)tag << 32) | (unsigned long long)__float_as_uint(p1);
            // fast path: two plain 8B stores, same 16B line (XCD L2)
            store_l2x2(fwb + par, k0, k1);
            // slow path: LLC-coherent packed atomics (placement-safe);
            // never waited on -- producers have no per-step vmcnt waits
            unsigned long long* sb = swb + par;
            __hip_atomic_store(sb, k0, __ATOMIC_RELAXED, __HIP_MEMORY_SCOPE_AGENT);
            __hip_atomic_store(sb + 1, k1, __ATOMIC_RELAXED, __HIP_MEMORY_SCOPE_AGENT);
        } else {
            const unsigned long long* fr = frb + par;
            const unsigned long long* sr = srb + par;
            float q0f, q1f;
            for (;;) {
                unsigned long long f0, f1;
                load_l2x2(fr, f0, f1);
                if ((unsigned)(f0 >> 32) == tag && (unsigned)(f1 >> 32) == tag) {
                    q0f = __uint_as_float((unsigned)f0);
                    q1f = __uint_as_float((unsigned)f1);
                    break;
                }
                unsigned long long a0q = __hip_atomic_load(
                    sr, __ATOMIC_RELAXED, __HIP_MEMORY_SCOPE_AGENT);
                unsigned long long a1q = __hip_atomic_load(
                    sr + 1, __ATOMIC_RELAXED, __HIP_MEMORY_SCOPE_AGENT);
                if ((unsigned)(a0q >> 32) == tag && (unsigned)(a1q >> 32) == tag) {
                    q0f = __uint_as_float((unsigned)a0q);
                    q1f = __uint_as_float((unsigned)a1q);
                    break;
                }
            }
            float g0 = p0 + q0f + bias0 + x0;
            float g1 = p1 + q1f + bias1 + x1;
            // half 0: g0=i-gate, g1=g-gate; half 1: g0=f-gate, g1=o-gate
            float e0 = sigmoid_fast(g0);
            float u, v;
            if (half == 0) { u = e0 * fast_tanh(g1); v = 0.f; }  // u = i*g
            else           { u = e0; v = sigmoid_fast(g1); }     // u = f, v = o
            float fx = __shfl_xor(u, 32);   // lanes<32 receive f
            float ox = __shfl_xor(v, 32);   // lanes<32 receive o
            if (half == 0) {
                c = fx * c + u;
                float h = ox * fast_tanh(c);
                h_sh[(s + 1) & 1][(qw << 5) + li] = h;
                int orow = dir ? srow : s;
                enc[((size_t)b * S_ + orow) * 512 + dir * H_ + base + (qw << 5) + li] =
                    (orow < len) ? h : 0.f;
            }
        }
        // ONE barrier per step, LDS-only wait: h(s+1) published; no vmcnt drain
        barrier_lds();

        srow = srow_n;
        x0 = x0n; x1 = x1n;
    }
}

// ---------------------------------------------------------------------------
// K3: U = enc@Ua^T, W = enc@Wa^T
// r12: grid (4,64)->(8,64), 16 s-rows/block (4 chunks of 4) -> 2 blocks/CU
// (was 1) to double latency hiding across the barrier-separated load phases.
// ---------------------------------------------------------------------------
__global__ __launch_bounds__(256) void uw_kernel(
    const float* __restrict__ enc, const float* __restrict__ Ua,
    const float* __restrict__ Wa, float* __restrict__ U, float* __restrict__ Wout) {
    __shared__ float wgt[60][129];
    __shared__ float erow[4][128];
    const int tid = threadIdx.x;
    const int b = blockIdx.y, s0 = blockIdx.x * 16;
    const int rl = tid >> 6;
    const int d = tid & 63;
    const int dd = d & 31;
    const int isW = d >> 5;
    float acc[4];
#pragma unroll
    for (int i = 0; i < 4; ++i) acc[i] = 0.f;

    for (int kk = 0; kk < 4; ++kk) {
        __syncthreads();
        for (int i = tid; i < 30 * 128; i += 256) {
            int r = i >> 7, k = i & 127;
            wgt[r][k] = Ua[(size_t)r * 512 + kk * 128 + k];
            wgt[r + 30][k] = Wa[(size_t)r * 512 + kk * 128 + k];
        }
        for (int chunk = 0; chunk < 4; ++chunk) {
            __syncthreads();
            for (int i = tid; i < 4 * 128; i += 256) {
                int r = i >> 7, k = i & 127;
                erow[r][k] = enc[((size_t)b * S_ + (s0 + chunk * 4 + r)) * 512 + kk * 128 + k];
            }
            __syncthreads();
            if (dd < HID_) {
                const float* wr = wgt[dd + 30 * isW];
                const float* er = erow[rl];
                float a = acc[chunk];
#pragma unroll
                for (int k = 0; k < 128; ++k) a = fmaf(er[k], wr[k], a);
                acc[chunk] = a;
            }
        }
    }
    if (dd < HID_) {
        float* dst = isW ? Wout : U;
#pragma unroll
        for (int chunk = 0; chunk < 4; ++chunk)
            dst[((size_t)b * S_ + (s0 + chunk * 4 + rl)) * 32 + dd] = acc[chunk];
    }
}

// ---------------------------------------------------------------------------
// K4: scores + predictions
// r12: grid (4,64)->(8,64), 16 i-rows/block (il=tid>>4, jb=(tid&15)*8,
// 8-wide j loop) -> 2 blocks/CU for latency hiding. Same total work.
// ---------------------------------------------------------------------------
__global__ __launch_bounds__(256) void scores_kernel(
    const float* __restrict__ U, const float* __restrict__ W,
    const float* __restrict__ va,
    float* __restrict__ scores, float* __restrict__ preds) {
    __shared__ float w_sh[128][31];
    const int b = blockIdx.y, i0 = blockIdx.x * 16;
    const int tid = threadIdx.x;

    float va_r[HID_];
#pragma unroll
    for (int d2 = 0; d2 < HID_; ++d2) va_r[d2] = va[d2];

    for (int i = tid; i < 128 * HID_; i += 256) {
        int r = i / HID_, d2 = i - r * HID_;
        w_sh[r][d2] = W[((size_t)b * S_ + r) * 32 + d2];
    }
    __syncthreads();

    const int il = tid >> 4;            // 0..15
    const int jb = (tid & 15) * 8;      // 0..120
    float u_r[HID_];
    const float* urow = U + ((size_t)b * S_ + i0 + il) * 32;
#pragma unroll
    for (int d2 = 0; d2 < HID_; ++d2) u_r[d2] = urow[d2];

    const size_t obase = ((size_t)b * S_ + (i0 + il)) * S_;
    for (int jj = 0; jj < 8; ++jj) {
        int j = jb + jj;
        float acc = 0.f;
#pragma unroll
        for (int d2 = 0; d2 < HID_; ++d2)
            acc = fmaf(va_r[d2], fast_tanh(u_r[d2] + w_sh[j][d2]), acc);
        scores[obase + j] = acc;
        preds[obase + j] = (sigmoid_acc(acc) >= 0.5f) ? 1.f : 0.f;
    }
}

// ---------------------------------------------------------------------------
// Workspace layout (bytes):
//   Xg   @ 0          : 2*8192*1024*4 = 67,108,864
//   enc  @ 67,108,864 : 64*128*512*4  = 16,777,216
//   U    @ 83,886,080 : 8192*32*4     =  1,048,576
//   W    @ 84,934,656 : 8192*32*4     =  1,048,576
//   Fch  @ 85,983,232 : 128*2*2*512*8 =  2,097,152
//   Sch  @ 88,080,384 : 128*2*2*512*8 =  2,097,152
//   sT   @ 90,177,536 : 16*1024*16    =    262,144   (total ~90.4 MB)
// ---------------------------------------------------------------------------
extern "C" void kernel_launch(void* const* d_in, const int* in_sizes, int n_in,
                              void* d_out, int out_size, void* d_ws, size_t ws_size,
                              hipStream_t stream) {
    (void)in_sizes; (void)n_in; (void)out_size; (void)ws_size;
    const int* concepts = (const int*)d_in[0];
    const int* lens = (const int*)d_in[1];
    const float* embedding = (const float*)d_in[2];
    const float* Wih_f = (const float*)d_in[3];
    const float* Whh_f = (const float*)d_in[4];
    const float* b_f = (const float*)d_in[5];
    const float* Wih_b = (const float*)d_in[6];
    const float* Whh_b = (const float*)d_in[7];
    const float* b_b = (const float*)d_in[8];
    const float* Ua = (const float*)d_in[9];
    const float* Wa = (const float*)d_in[10];
    const float* va = (const float*)d_in[11];

    char* ws = (char*)d_ws;
    float* Xg = (float*)(ws + 0);
    float* enc = (float*)(ws + 67108864);
    float* U = (float*)(ws + 83886080);
    float* W = (float*)(ws + 84934656);
    unsigned long long* Fch = (unsigned long long*)(ws + 85983232);
    unsigned long long* Sch = (unsigned long long*)(ws + 88080384);
    float4* sT = (float4*)(ws + 90177536);

    float* scores = (float*)d_out;
    float* preds = scores + (size_t)B_ * S_ * S_;

    // prep folds the Fch+Sch zeroing (was hipMemsetAsync) -- one less dispatch
    hipLaunchKernelGGL(prep_stream_kernel, dim3(64), dim3(256), 0, stream,
                       Whh_f, Whh_b, sT, Fch);
    hipLaunchKernelGGL(gemm2_kernel, dim3(512, 2), dim3(256), 0, stream,
                       concepts, embedding, Wih_f, Wih_b, Xg);

    {
        const float* XgA = Xg;
        void* ka[] = {(void*)&XgA, (void*)&Whh_f, (void*)&Whh_b, (void*)&b_f,
                      (void*)&b_b, (void*)&lens, (void*)&enc, (void*)&Fch,
                      (void*)&Sch, (void*)&sT};
        (void)hipLaunchCooperativeKernel((const void*)lstm_ks3_kernel, dim3(256),
                                         dim3(512), ka,
                                         LPD_ * 512 * sizeof(float4), stream);
    }

    hipLaunchKernelGGL(uw_kernel, dim3(8, 64), dim3(256), 0, stream,
                       enc, Ua, Wa, U, W);
    hipLaunchKernelGGL(scores_kernel, dim3(8, 64), dim3(256), 0, stream,
                       U, W, va, scores, preds);
}